// Round 3
// baseline (251.820 us; speedup 1.0000x reference)
//
#include <hip/hip_runtime.h>
#include <cstdint>

#define NPOINTS 524288
#define NLEV 24
#define CAP 262144
#define HASHMUL 2531011u
#define PTS_PER_BLOCK 512
#define BLOCKS_PER_LEVEL (NPOINTS / PTS_PER_BLOCK)   // 1024

// Per-point simplex setup: outputs 4 table indices + 4 barycentric weights.
// Bit-exact op ordering vs the JAX reference (see round-0 notes).
__device__ __forceinline__ void prep_point(
    const float p0, const float p1, const float p2,
    const float sf0, const float sf1, const float sf2,
    const float sh0, const float sh1, const float sh2,
    uint32_t* __restrict__ ix, float* __restrict__ w)
{
    const float cf0 = (p0 + sh0) * sf0;
    const float cf1 = (p1 + sh1) * sf1;
    const float cf2 = (p2 + sh2) * sf2;

    const float S2 = cf2;
    const float S1 = cf2 + cf1;
    const float S0 = S1 + cf0;

    float E[4];
    E[0] = S0;
    E[1] = S1 - 1.0f*cf0;
    E[2] = S2 - 2.0f*cf1;
    E[3] = 0.0f - 3.0f*cf2;

    float rem0[4];
    float sumrem = 0.0f;
    #pragma unroll
    for (int i = 0; i < 4; ++i) {
        float v  = E[i] * 0.25f;
        float up = ceilf(v)  * 4.0f;
        float dn = floorf(v) * 4.0f;
        rem0[i] = (up - E[i] < E[i] - dn) ? up : dn;
        sumrem += rem0[i];
    }
    const int sum_val = (int)rintf(sumrem * 0.25f);

    float diff[4];
    #pragma unroll
    for (int i = 0; i < 4; ++i) diff[i] = E[i] - rem0[i];

    int rank[4];
    #pragma unroll
    for (int i = 0; i < 4; ++i) {
        int rk = 0;
        #pragma unroll
        for (int j = 0; j < 4; ++j) {
            if (j > i)      rk += (diff[j] >  diff[i]) ? 1 : 0;
            else if (j < i) rk += (diff[j] >= diff[i]) ? 1 : 0;
        }
        rk += sum_val;
        if (rk < 0)      { rk += 4; rem0[i] += 4.0f; }
        else if (rk > 3) { rk -= 4; rem0[i] -= 4.0f; }
        rank[i] = rk;
    }

    float delta[4];
    #pragma unroll
    for (int i = 0; i < 4; ++i) delta[i] = (E[i] - rem0[i]) * 0.25f;

    float b[5];
    #pragma unroll
    for (int k = 0; k < 5; ++k) {
        float acc = 0.0f;
        #pragma unroll
        for (int i = 0; i < 4; ++i) {
            int ti = 3 - rank[i];
            float m = ((ti == k) ? 1.0f : 0.0f) - ((ti == (k-1)) ? 1.0f : 0.0f);
            acc += delta[i] * m;
        }
        b[k] = acc;
    }
    b[0] += 1.0f + b[4];

    int rem0i[4];
    #pragma unroll
    for (int i = 0; i < 4; ++i) rem0i[i] = (int)rintf(rem0[i]);

    #pragma unroll
    for (int r = 0; r < 4; ++r) {
        uint32_t h = 0u;
        #pragma unroll
        for (int i = 0; i < 3; ++i) {
            int key = rem0i[i] + r - 4 * ((rank[i] > 3 - r) ? 1 : 0);
            h = (h + (uint32_t)key) * HASHMUL;
        }
        ix[r] = h & (uint32_t)(CAP - 1);
        w[r]  = b[r];
    }
}

// One block = (one level, 512 consecutive points), 2 points per thread.
// blockIdx swizzled so XCD x handles levels {x, x+8, x+16} sequentially.
template <bool USE_WS>
__global__ __launch_bounds__(256, 6) void permuto_kernel(
    const float* __restrict__ pos,      // [N,3]
    const float* __restrict__ lattice,  // [L,C,2]
    const float* __restrict__ shift,    // [L,3]
    const float* __restrict__ anneal,   // [L]
    const float* __restrict__ scale,    // [L]
    float2* __restrict__ ws,            // [L][N] float2 (level-major)
    float* __restrict__ out)            // [N, L*2] (direct fallback)
{
    __shared__ float s_pos[PTS_PER_BLOCK * 3];   // 6 KB

    const int t    = threadIdx.x;
    const int bid  = blockIdx.x;
    const int xcd  = bid & 7;
    const int slot = bid >> 3;                   // 0..3071
    const int l    = xcd + 8 * (slot >> 10);     // level
    const int nb   = slot & (BLOCKS_PER_LEVEL - 1);
    const int pbase = nb * PTS_PER_BLOCK;        // first point of block

    // coalesced position staging: 1536 floats, 6 per thread
    {
        const float* src = pos + (size_t)pbase * 3;
        #pragma unroll
        for (int k = 0; k < 6; ++k)
            s_pos[k * 256 + t] = src[k * 256 + t];
    }

    // block-uniform level constants (scalar)
    const float sc  = scale[l];
    const float sf0 = sc / sqrtf(2.0f);
    const float sf1 = sc / sqrtf(6.0f);
    const float sf2 = sc / sqrtf(12.0f);
    const float sh0 = shift[l*3+0];
    const float sh1 = shift[l*3+1];
    const float sh2 = shift[l*3+2];
    const float an  = anneal[l];

    __syncthreads();

    // point A = local t, point B = local t+256
    const float a0 = s_pos[3*t+0], a1 = s_pos[3*t+1], a2 = s_pos[3*t+2];
    const float b0 = s_pos[3*(t+256)+0], b1 = s_pos[3*(t+256)+1], b2 = s_pos[3*(t+256)+2];

    uint32_t ixA[4], ixB[4];
    float    wA[4],  wB[4];
    prep_point(a0, a1, a2, sf0, sf1, sf2, sh0, sh1, sh2, ixA, wA);
    prep_point(b0, b1, b2, sf0, sf1, sf2, sh0, sh1, sh2, ixB, wB);

    const float2* __restrict__ tbl =
        reinterpret_cast<const float2*>(lattice) + (size_t)l * CAP;

    // issue all 8 gathers back-to-back (max MLP), then accumulate
    float2 vA[4], vB[4];
    #pragma unroll
    for (int r = 0; r < 4; ++r) vA[r] = tbl[ixA[r]];
    #pragma unroll
    for (int r = 0; r < 4; ++r) vB[r] = tbl[ixB[r]];

    float oA0 = 0.f, oA1 = 0.f, oB0 = 0.f, oB1 = 0.f;
    #pragma unroll
    for (int r = 0; r < 4; ++r) {
        oA0 += wA[r] * vA[r].x;  oA1 += wA[r] * vA[r].y;
        oB0 += wB[r] * vB[r].x;  oB1 += wB[r] * vB[r].y;
    }

    float2 resA, resB;
    resA.x = oA0 * an;  resA.y = oA1 * an;
    resB.x = oB0 * an;  resB.y = oB1 * an;

    if (USE_WS) {
        // nontemporal: don't let the streaming ws writes evict the table from L2
        float2* pA = ws + (size_t)l * NPOINTS + pbase + t;
        float2* pB = pA + 256;
        __builtin_nontemporal_store(resA.x, &pA->x);
        __builtin_nontemporal_store(resA.y, &pA->y);
        __builtin_nontemporal_store(resB.x, &pB->x);
        __builtin_nontemporal_store(resB.y, &pB->y);
    } else {
        *reinterpret_cast<float2*>(out + (size_t)(pbase + t) * (NLEV*2) + l*2) = resA;
        *reinterpret_cast<float2*>(out + (size_t)(pbase + 256 + t) * (NLEV*2) + l*2) = resB;
    }
}

// Transpose [L][N] float2 -> [N][48] float. 128 points per block.
__global__ __launch_bounds__(256) void transpose_kernel(
    const float* __restrict__ ws,
    float* __restrict__ out)
{
    __shared__ float lds[128 * 49];
    const int t  = threadIdx.x;
    const int n0 = blockIdx.x * 128;

    #pragma unroll
    for (int l = 0; l < NLEV; ++l) {
        const float v = ws[(size_t)l * (NPOINTS*2) + (size_t)n0 * 2 + t];
        const int p = t >> 1;
        const int f = t & 1;
        lds[p * 49 + l * 2 + f] = v;
    }
    __syncthreads();

    const size_t obase = (size_t)n0 * 48;
    #pragma unroll
    for (int it = 0; it < 24; ++it) {
        const int flat = it * 256 + t;
        const int p = flat / 48;
        const int c = flat - p * 48;
        out[obase + flat] = lds[p * 49 + c];
    }
}

extern "C" void kernel_launch(void* const* d_in, const int* in_sizes, int n_in,
                              void* d_out, int out_size, void* d_ws, size_t ws_size,
                              hipStream_t stream) {
    const float* pos     = (const float*)d_in[0];
    const float* lattice = (const float*)d_in[1];
    const float* shift   = (const float*)d_in[2];
    const float* anneal  = (const float*)d_in[3];
    const float* scale   = (const float*)d_in[4];
    float* out = (float*)d_out;

    const int grid = NLEV * BLOCKS_PER_LEVEL;    // 24576
    const size_t ws_needed = (size_t)NLEV * NPOINTS * 2 * sizeof(float);

    if (ws_size >= ws_needed) {
        float2* ws = (float2*)d_ws;
        permuto_kernel<true><<<grid, 256, 0, stream>>>(
            pos, lattice, shift, anneal, scale, ws, out);
        transpose_kernel<<<NPOINTS / 128, 256, 0, stream>>>(
            (const float*)d_ws, out);
    } else {
        permuto_kernel<false><<<grid, 256, 0, stream>>>(
            pos, lattice, shift, anneal, scale, nullptr, out);
    }
}